// Round 9
// baseline (189.776 us; speedup 1.0000x reference)
//
#include <hip/hip_runtime.h>

#define M 4096
#define L 32
#define K 64
#define NBLK 256
#define BLOCK 256
#define NPW 4                     // nodes per wave (4 waves -> 16 nodes/block)
#define NPB 16                    // nodes per block
#define MK (M * K)
#define FB 0xAAAAAAAAu            // ws poison; round tag = FB + round (r>=1)

// Persistent kernel (R9): dataflow-tagged exchange, ONE sync per round.
// 256 blocks x 256 threads; wave w of block b owns nodes base..base+3.
//
// R8 flaw fixed here: __syncthreads forces s_waitcnt vmcnt(0), and R8 had
// sync AFTER prefetch-issue but BEFORE the tag-verify -> every round ate the
// full 2MB device-wide prefetch drain on the critical path. R9:
//  - LDS sv double-buffered (2x16KB) -> no "protect old sv" sync; the ONLY
//    sync sits after verify+LDS-write, when prefetch has already drained
//    during the tag-wait.
//  - tag loads issued BEFORE prefetch: vmcnt retires in issue order, so the
//    verify waits at vmcnt(prefetch_count) — tag data ready, prefetch still
//    in flight. The tag-wait is the latency-hider again.
// Publish: (FB+r)<<32 | f32bits as one aligned 8B sc1 store (tag visible =>
// value visible). Double-buffered exchange; skew between blocks provably
// <2 rounds (a block publishes r+1 only after verifying ALL of round r).
// Poison hi-word FB+0 never matches a real tag -> no memset dispatch.
__global__ __launch_bounds__(BLOCK)
void net_kernel(const float* __restrict__ x,
                const float* __restrict__ w_in,
                const float* __restrict__ b_in,
                const float* __restrict__ w,
                const float* __restrict__ b,
                const int* __restrict__ igraf,
                float* __restrict__ out,
                unsigned long long* __restrict__ buf)   // 2 x M u64
{
    __shared__ float sv[2][M];   // double-buffered value vector (32 KB)

    const int tid  = threadIdx.x;
    const int blk  = blockIdx.x;
    const int wave = tid >> 6;
    const int lane = tid & 63;
    const int base = blk * NPB + wave * NPW;
    const bool lastblk = (blk == NBLK - 1);   // owns node M-1

    // Layer-0 fragment prefetch (4 nodes/wave; bias on lanes 0-3).
    float wv[NPW]; int iv[NPW]; float breg = 0.0f;
    {
        const size_t b0 = (size_t)base * K + (size_t)lane;
        #pragma unroll
        for (int j = 0; j < NPW; ++j) {
            wv[j] = w[b0 + (size_t)j * K];
            iv[j] = igraf[b0 + (size_t)j * K];
        }
        if (lane < NPW) breg = b[base + lane];
    }

    // v0 = relu(w_in * x + b_in): 4 float4 per thread, into sv[0].
    #pragma unroll
    for (int j = 0; j < 4; ++j) {
        const int idx = tid + j * BLOCK;
        const float4 x4 = ((const float4*)x)[idx];
        const float4 wi = ((const float4*)w_in)[idx];
        const float4 bi = ((const float4*)b_in)[idx];
        float4 r;
        r.x = fmaxf(fmaf(wi.x, x4.x, bi.x), 0.0f);
        r.y = fmaxf(fmaf(wi.y, x4.y, bi.y), 0.0f);
        r.z = fmaxf(fmaf(wi.z, x4.z, bi.z), 0.0f);
        r.w = fmaxf(fmaf(wi.w, x4.w, bi.w), 0.0f);
        ((float4*)sv[0])[idx] = r;
    }
    __syncthreads();

    int cur = 0;
    for (int l = 0; l < L; ++l) {
        // Gather + product, 4 independent nodes, from sv[cur].
        float p[NPW];
        #pragma unroll
        for (int j = 0; j < NPW; ++j) p[j] = wv[j] * sv[cur][iv[j]];

        // 4 independent 64-lane butterfly reductions.
        #pragma unroll
        for (int j = 0; j < NPW; ++j) {
            #pragma unroll
            for (int off = 32; off > 0; off >>= 1)
                p[j] += __shfl_xor(p[j], off, 64);
        }

        // Lane j (j<4) finalizes node base+j.
        float pj = p[0];
        pj = (lane == 1) ? p[1] : pj;
        pj = (lane == 2) ? p[2] : pj;
        pj = (lane == 3) ? p[3] : pj;
        const float val = 1.0f / (1.0f + __expf(-(pj + breg)));

        if (l == L - 1) {
            // Only block 255 reaches l=31; unique writer wave3 lane3 = node 4095.
            if (wave == 3 && lane == 3) out[0] = val;
            break;
        }

        const unsigned tag = FB + (unsigned)(l + 1);
        unsigned long long* bufr = buf + (size_t)((l + 1) & 1) * M;

        // ---- publish: tagged 8B store, fire-and-forget ----
        if (lane < NPW) {
            const unsigned long long pk =
                ((unsigned long long)tag << 32) |
                (unsigned long long)__float_as_uint(val);
            __hip_atomic_store(&bufr[base + lane], pk,
                               __ATOMIC_RELAXED, __HIP_MEMORY_SCOPE_AGENT);
        }

        if ((l == L - 2) && !lastblk) return;  // all but block 255 done

        // ---- tag loads FIRST: verify will wait only on these (issue order)
        unsigned long long vals[16];
        #pragma unroll
        for (int j = 0; j < 16; ++j)
            vals[j] = __hip_atomic_load(&bufr[tid + j * BLOCK],
                                        __ATOMIC_RELAXED,
                                        __HIP_MEMORY_SCOPE_AGENT);

        // ---- prefetch AFTER: stays in flight through the verify wait ----
        if ((l + 2 < L) || lastblk) {
            const size_t nb = (size_t)(l + 1) * MK + (size_t)base * K + (size_t)lane;
            #pragma unroll
            for (int j = 0; j < NPW; ++j) {
                wv[j] = w[nb + (size_t)j * K];
                iv[j] = igraf[nb + (size_t)j * K];
            }
            if (lane < NPW) breg = b[(l + 1) * M + base + lane];
        }

        // ---- verify tags; re-load only stale entries ----
        for (;;) {
            bool ok = true;
            #pragma unroll
            for (int j = 0; j < 16; ++j) {
                if ((unsigned)(vals[j] >> 32) != tag) {
                    ok = false;
                    vals[j] = __hip_atomic_load(&bufr[tid + j * BLOCK],
                                                __ATOMIC_RELAXED,
                                                __HIP_MEMORY_SCOPE_AGENT);
                }
            }
            if (ok) break;
            __builtin_amdgcn_s_sleep(1);
        }

        // ---- stage verified values into the OTHER LDS buffer ----
        const int nxt = cur ^ 1;
        #pragma unroll
        for (int j = 0; j < 16; ++j)
            sv[nxt][tid + j * BLOCK] = __uint_as_float((unsigned)vals[j]);

        // The ONLY sync this round: prefetch has drained during the verify
        // wait, so the vmcnt(0)-before-barrier is (mostly) free now.
        __syncthreads();
        cur = nxt;
    }
}

extern "C" void kernel_launch(void* const* d_in, const int* in_sizes, int n_in,
                              void* d_out, int out_size, void* d_ws, size_t ws_size,
                              hipStream_t stream) {
    const float* x     = (const float*)d_in[0];
    const float* w_in  = (const float*)d_in[1];
    const float* b_in  = (const float*)d_in[2];
    const float* wt    = (const float*)d_in[3];
    const float* b     = (const float*)d_in[4];
    const int*   igraf = (const int*)d_in[5];
    float*       out   = (float*)d_out;

    unsigned long long* buf = (unsigned long long*)d_ws;   // 2 x M x 8B = 64KB

    // No memset: poison hi-word = FB+0 never matches a round tag (FB+r, r>=1).
    hipLaunchKernelGGL(net_kernel, dim3(NBLK), dim3(BLOCK), 0, stream,
                       x, w_in, b_in, wt, b, igraf, out, buf);
    (void)in_sizes; (void)n_in; (void)out_size; (void)ws_size;
}